// Round 10
// baseline (2512.193 us; speedup 1.0000x reference)
//
#include <hip/hip_runtime.h>
#include <math.h>

#define N_NODES 50000
#define N_EDGES 600000
#define IN_DIM 64
#define DMODEL 128
#define N_LAYERS 8
#define N_ETYPES 44
#define N_MENTIONS 100000
#define N_VARS 20000
#define OUT_DIM 100

#define EPI_BIAS 0
#define EPI_BIAS_RELU 1
#define EPI_DEG_GELU 2
#define EPI_NONE 3

#define SCL  6.103515625e-05f   /* 2^-14: pre-scale into f16 range (|h| can reach ~1e7) */
#define SCLI 16384.0f

typedef _Float16 f16x8 __attribute__((ext_vector_type(8)));
typedef _Float16 f16x4 __attribute__((ext_vector_type(4)));
typedef float f32x4 __attribute__((ext_vector_type(4)));

__device__ __forceinline__ float gelu_exact(float x) {
    return 0.5f * x * (1.0f + erff(x * 0.70710678118654752f));
}

// ---------------- weight prep: transpose [K,N]->[Npad,K] and split fp32 -> f16 hi+lo ----------
__global__ void wprep(const float* __restrict__ src, _Float16* __restrict__ dhi,
                      _Float16* __restrict__ dlo, int K, int Nsrc, int Npad,
                      long srcLS, long dstLS, int cat) {
    __shared__ float sh[16][17];
    int z = blockIdx.z;
    src += (size_t)z * srcLS;
    dhi += (size_t)z * dstLS;
    dlo += (size_t)z * dstLS;
    int n0 = blockIdx.x * 16, k0 = blockIdx.y * 16;
    int tx = threadIdx.x, ty = threadIdx.y;
    int nr = n0 + tx, kr = k0 + ty;
    float v;
    if (cat) {
        int half = nr >> 8;
        int nc = nr & 255;
        v = src[(size_t)(kr + half * 128) * 256 + nc];
    } else {
        v = (nr < Nsrc) ? src[(size_t)kr * Nsrc + nr] : 0.f;
    }
    sh[ty][tx] = v;
    __syncthreads();
    float x = sh[tx][ty];
    int n = n0 + ty, k = k0 + tx;
    _Float16 hi = (_Float16)x;
    float lo = x - (float)hi;
    dhi[(size_t)n * K + k] = hi;
    dlo[(size_t)n * K + k] = (_Float16)lo;
}

// ---------------- 3xF16 MFMA GEMM, 64x64 tile ----------------
template<int EPI, int ASPLIT, int OSPLIT>
__global__ __launch_bounds__(256) void gemm3h(
        const float* __restrict__ A, const _Float16* __restrict__ Ahi,
        const _Float16* __restrict__ Alo,
        const _Float16* __restrict__ Bh, const _Float16* __restrict__ Bl,
        const float* __restrict__ bias, const int* __restrict__ deg,
        float* __restrict__ C, _Float16* __restrict__ Chi, _Float16* __restrict__ Clo,
        int M, int N, int K, int ldC) {
    __shared__ _Float16 Ah[64 * 56], Al[64 * 56], Bsh[64 * 56], Bsl[64 * 56];
    int t = threadIdx.x;
    int m0 = blockIdx.y * 64, n0 = blockIdx.x * 64;
    int ar = t >> 2, ac = (t & 3) * 8;
    int btt = t & 127, br = btt >> 1, bc = (btt & 1) * 16;
    const _Float16* Bsrc = (t < 128) ? Bh : Bl;
    _Float16* Bdst = (t < 128) ? Bsh : Bsl;
    int lane = t & 63, wid = t >> 6;
    int wm = (wid >> 1) * 32, wn = (wid & 1) * 32;
    int quad = lane >> 4, l15 = lane & 15;
    f32x4 acc[2][2] = {};
    bool arow_ok = (m0 + ar) < M;
    const float* Aptr = ASPLIT ? nullptr : (A + (size_t)(m0 + ar) * K + ac);
    const _Float16* Ahp = ASPLIT ? (Ahi + (size_t)(m0 + ar) * K + ac) : nullptr;
    const _Float16* Alp = ASPLIT ? (Alo + (size_t)(m0 + ar) * K + ac) : nullptr;
    const _Float16* Bptr = Bsrc + (size_t)(n0 + br) * K + bc;

    for (int k0 = 0; k0 < K; k0 += 32) {
        f16x8 hv = {}, lv = {};
        if (ASPLIT) {
            if (arow_ok) {
                hv = *(const f16x8*)(Ahp + k0);
                lv = *(const f16x8*)(Alp + k0);
            }
        } else {
            float4 v0 = {0, 0, 0, 0}, v1 = {0, 0, 0, 0};
            if (arow_ok) {
                v0 = *(const float4*)(Aptr + k0);
                v1 = *(const float4*)(Aptr + k0 + 4);
            }
            float xs[8] = {v0.x, v0.y, v0.z, v0.w, v1.x, v1.y, v1.z, v1.w};
#pragma unroll
            for (int j = 0; j < 8; j++) {
                float s = xs[j] * SCL;
                _Float16 h = (_Float16)s;
                hv[j] = h;
                lv[j] = (_Float16)(s - (float)h);
            }
        }
        *(f16x8*)&Ah[ar * 56 + ac] = hv;
        *(f16x8*)&Al[ar * 56 + ac] = lv;
        f16x8 b0 = *(const f16x8*)(Bptr + k0);
        f16x8 b1v = *(const f16x8*)(Bptr + k0 + 8);
        *(f16x8*)&Bdst[br * 56 + bc] = b0;
        *(f16x8*)&Bdst[br * 56 + bc + 8] = b1v;
        __syncthreads();

        f16x8 afh[2], afl[2], bfh[2], bfl[2];
#pragma unroll
        for (int i = 0; i < 2; i++) {
            int am = (wm + i * 16 + l15) * 56 + quad * 8;
            afh[i] = *(const f16x8*)&Ah[am];
            afl[i] = *(const f16x8*)&Al[am];
            int bn = (wn + i * 16 + l15) * 56 + quad * 8;
            bfh[i] = *(const f16x8*)&Bsh[bn];
            bfl[i] = *(const f16x8*)&Bsl[bn];
        }
#pragma unroll
        for (int i = 0; i < 2; i++)
#pragma unroll
            for (int j = 0; j < 2; j++) {
                acc[i][j] = __builtin_amdgcn_mfma_f32_16x16x32_f16(afh[i], bfh[j], acc[i][j], 0, 0, 0);
                acc[i][j] = __builtin_amdgcn_mfma_f32_16x16x32_f16(afh[i], bfl[j], acc[i][j], 0, 0, 0);
                acc[i][j] = __builtin_amdgcn_mfma_f32_16x16x32_f16(afl[i], bfh[j], acc[i][j], 0, 0, 0);
            }
        __syncthreads();
    }

#pragma unroll
    for (int i = 0; i < 2; i++) {
        int rowb = m0 + wm + i * 16 + quad * 4;
#pragma unroll
        for (int j = 0; j < 2; j++) {
            int col = n0 + wn + j * 16 + l15;
            if (col >= N) continue;
#pragma unroll
            for (int r = 0; r < 4; r++) {
                int row = rowb + r;
                if (row >= M) continue;
                float v = acc[i][j][r] * SCLI;
                if (EPI == EPI_BIAS) { v += bias[col]; }
                else if (EPI == EPI_BIAS_RELU) { v += bias[col]; v = fmaxf(v, 0.f); }
                else if (EPI == EPI_DEG_GELU) { v += (float)deg[row] * bias[col]; v = gelu_exact(v); }
                size_t idx = (size_t)row * ldC + col;
                if (OSPLIT) {
                    float s = v * SCL;
                    _Float16 h = (_Float16)s;
                    Chi[idx] = h;
                    Clo[idx] = (_Float16)(s - (float)h);
                } else {
                    C[idx] = v;
                }
            }
        }
    }
}

// ---------------- FUSED W2(layer l) + W1(layer l+1) ----------------
// Phase 1: h64 = gelu(P[m0:m0+64] @ W2 + deg*b2), P/W2 frags direct from global (W2 L2-resident).
// h64 parked in LDS as pre-scaled f16 hi/lo (bit-identical to the old global round-trip).
// Phase 2: HH[m0:m0+64, 0:512] = (h64 @ W1next) * SCLI, A from LDS, W1 frags direct from L2.
#define HST 136  /* h-tile LDS row stride (f16): 16B-aligned, 2-way bank aliasing (free) */
__global__ __launch_bounds__(256) void w2w1(
        const _Float16* __restrict__ Phi, const _Float16* __restrict__ Plo,
        const _Float16* __restrict__ W2h, const _Float16* __restrict__ W2l,
        const float* __restrict__ b2, const int* __restrict__ deg,
        const _Float16* __restrict__ W1h, const _Float16* __restrict__ W1l,
        float* __restrict__ HH) {
    __shared__ _Float16 hH[64 * HST], hL[64 * HST];
    int t = threadIdx.x, lane = t & 63, wid = t >> 6;
    int quad = lane >> 4, l15 = lane & 15;
    int m0 = blockIdx.x * 64;

    // ---- Phase 1: 64x128, K=256 ----
    f32x4 acc1[8] = {};
    int arow = m0 + wid * 16 + l15;
    int arows = (arow < N_NODES) ? arow : (N_NODES - 1);  // clamp: safe read, write guarded
    const _Float16* pAh = Phi + (size_t)arows * 256 + quad * 8;
    const _Float16* pAl = Plo + (size_t)arows * 256 + quad * 8;
    for (int k0 = 0; k0 < 256; k0 += 32) {
        f16x8 ah = *(const f16x8*)(pAh + k0);
        f16x8 al = *(const f16x8*)(pAl + k0);
#pragma unroll
        for (int j = 0; j < 8; j++) {
            size_t boff = (size_t)(j * 16 + l15) * 256 + k0 + quad * 8;
            f16x8 bh = *(const f16x8*)(W2h + boff);
            f16x8 bl = *(const f16x8*)(W2l + boff);
            acc1[j] = __builtin_amdgcn_mfma_f32_16x16x32_f16(ah, bh, acc1[j], 0, 0, 0);
            acc1[j] = __builtin_amdgcn_mfma_f32_16x16x32_f16(ah, bl, acc1[j], 0, 0, 0);
            acc1[j] = __builtin_amdgcn_mfma_f32_16x16x32_f16(al, bh, acc1[j], 0, 0, 0);
        }
    }
    int rl0 = wid * 16 + quad * 4;
#pragma unroll
    for (int j = 0; j < 8; j++) {
        int col = j * 16 + l15;
#pragma unroll
        for (int r = 0; r < 4; r++) {
            int row = m0 + rl0 + r;
            if (row < N_NODES) {
                float v = acc1[j][r] * SCLI + (float)deg[row] * b2[col];
                v = gelu_exact(v);
                float s = v * SCL;
                _Float16 h = (_Float16)s;
                hH[(rl0 + r) * HST + col] = h;
                hL[(rl0 + r) * HST + col] = (_Float16)(s - (float)h);
            }
        }
    }
    __syncthreads();

    // ---- Phase 2: 64x512, K=128, two N-halves of 256 ----
    for (int pass = 0; pass < 2; pass++) {
        f32x4 acc2[16] = {};
        for (int k0 = 0; k0 < 128; k0 += 32) {
            f16x8 ah = *(const f16x8*)&hH[(wid * 16 + l15) * HST + k0 + quad * 8];
            f16x8 al = *(const f16x8*)&hL[(wid * 16 + l15) * HST + k0 + quad * 8];
#pragma unroll
            for (int j = 0; j < 16; j++) {
                size_t boff = (size_t)(pass * 256 + j * 16 + l15) * 128 + k0 + quad * 8;
                f16x8 bh = *(const f16x8*)(W1h + boff);
                f16x8 bl = *(const f16x8*)(W1l + boff);
                acc2[j] = __builtin_amdgcn_mfma_f32_16x16x32_f16(ah, bh, acc2[j], 0, 0, 0);
                acc2[j] = __builtin_amdgcn_mfma_f32_16x16x32_f16(ah, bl, acc2[j], 0, 0, 0);
                acc2[j] = __builtin_amdgcn_mfma_f32_16x16x32_f16(al, bh, acc2[j], 0, 0, 0);
            }
        }
#pragma unroll
        for (int j = 0; j < 16; j++) {
            int col = pass * 256 + j * 16 + l15;
#pragma unroll
            for (int r = 0; r < 4; r++) {
                int row = m0 + rl0 + r;
                if (row < N_NODES)
                    HH[(size_t)row * 512 + col] = acc2[j][r] * SCLI;
            }
        }
    }
}

// ---------------- CSR build ----------------
__global__ void count_deg(const int* __restrict__ dst, int* __restrict__ deg) {
    int e = blockIdx.x * blockDim.x + threadIdx.x;
    if (e < N_EDGES) atomicAdd(&deg[dst[e]], 1);
}

#define SCAN_B 1024
#define SCAN_NB ((N_NODES + SCAN_B - 1) / SCAN_B)

__global__ void scan_local(const int* __restrict__ deg, int* __restrict__ offs,
                           int* __restrict__ bsum, int n) {
    __shared__ int sh[SCAN_B];
    int t = threadIdx.x;
    int i = blockIdx.x * SCAN_B + t;
    int v = (i < n) ? deg[i] : 0;
    sh[t] = v;
    __syncthreads();
    for (int o = 1; o < SCAN_B; o <<= 1) {
        int u = (t >= o) ? sh[t - o] : 0;
        __syncthreads();
        sh[t] += u;
        __syncthreads();
    }
    if (i < n) offs[i] = sh[t] - v;
    if (t == SCAN_B - 1) bsum[blockIdx.x] = sh[t];
}

__global__ void scan_block(int* __restrict__ bsum, int nb) {
    __shared__ int sh[64];
    int t = threadIdx.x;
    int v = (t < nb) ? bsum[t] : 0;
    sh[t] = v;
    __syncthreads();
    for (int o = 1; o < 64; o <<= 1) {
        int u = (t >= o) ? sh[t - o] : 0;
        __syncthreads();
        sh[t] += u;
        __syncthreads();
    }
    if (t < nb) bsum[t] = sh[t] - v;
}

__global__ void scan_final(int* __restrict__ offs, const int* __restrict__ bsum,
                           int* __restrict__ cursor, int n, int total) {
    int i = blockIdx.x * SCAN_B + threadIdx.x;
    if (i < n) {
        int o = offs[i] + bsum[blockIdx.x];
        offs[i] = o;
        cursor[i] = o;
    }
    if (i == n) offs[n] = total;
}

__global__ void place_edges(const int* __restrict__ src, const int* __restrict__ dst,
                            const int* __restrict__ lab, int* __restrict__ cursor,
                            int* __restrict__ src_s, int* __restrict__ lab_s) {
    int e = blockIdx.x * blockDim.x + threadIdx.x;
    if (e < N_EDGES) {
        int pos = atomicAdd(&cursor[dst[e]], 1);
        src_s[pos] = src[e];
        lab_s[pos] = lab[e];
    }
}

// ---------------- per-etype projection, all layers in one dispatch ----------------
__global__ void etype_proj_all(const float* __restrict__ edge_emb, const float* __restrict__ mlp_W1,
                               const float* __restrict__ mlp_b1, float* __restrict__ etp_all) {
    int et = blockIdx.x;
    int l  = blockIdx.y;
    int c = threadIdx.x;  // 256
    const float* ee = edge_emb + (size_t)l * N_ETYPES * DMODEL + (size_t)et * DMODEL;
    const float* W  = mlp_W1 + (size_t)l * 384 * 256 + (size_t)256 * 256;
    float s = mlp_b1[(size_t)l * 256 + c];
    for (int k = 0; k < DMODEL; k++)
        s += ee[k] * W[(size_t)k * 256 + c];
    etp_all[((size_t)l * N_ETYPES + et) * 256 + c] = s;
}

// ---------------- edge aggregation: wave-per-node, unroll x4 (round-6 proven form) ----------------
__global__ __launch_bounds__(256) void edge_agg(
        const float* __restrict__ HH, const float* __restrict__ etp,
        const int* __restrict__ offsets, const int* __restrict__ src_s,
        const int* __restrict__ lab_s, _Float16* __restrict__ Phi,
        _Float16* __restrict__ Plo) {
    int wid = threadIdx.x >> 6, tl = threadIdx.x & 63;
    int i = blockIdx.x * 4 + wid;
    if (i >= N_NODES) return;
    int c4 = tl * 4;
    float4 hd = *(const float4*)&HH[(size_t)i * 512 + c4];
    float4 acc = {0.f, 0.f, 0.f, 0.f};
    int e0 = offsets[i], e1 = offsets[i + 1];
    int e = e0;
    for (; e + 3 < e1; e += 4) {
        int s0 = src_s[e],     l0 = lab_s[e];
        int s1 = src_s[e + 1], l1 = lab_s[e + 1];
        int s2 = src_s[e + 2], l2 = lab_s[e + 2];
        int s3 = src_s[e + 3], l3 = lab_s[e + 3];
        float4 hs0 = *(const float4*)&HH[(size_t)s0 * 512 + 256 + c4];
        float4 hs1 = *(const float4*)&HH[(size_t)s1 * 512 + 256 + c4];
        float4 hs2 = *(const float4*)&HH[(size_t)s2 * 512 + 256 + c4];
        float4 hs3 = *(const float4*)&HH[(size_t)s3 * 512 + 256 + c4];
        float4 et0 = *(const float4*)&etp[l0 * 256 + c4];
        float4 et1 = *(const float4*)&etp[l1 * 256 + c4];
        float4 et2 = *(const float4*)&etp[l2 * 256 + c4];
        float4 et3 = *(const float4*)&etp[l3 * 256 + c4];
        acc.x += fmaxf(hd.x + hs0.x + et0.x, 0.f) + fmaxf(hd.x + hs1.x + et1.x, 0.f)
               + fmaxf(hd.x + hs2.x + et2.x, 0.f) + fmaxf(hd.x + hs3.x + et3.x, 0.f);
        acc.y += fmaxf(hd.y + hs0.y + et0.y, 0.f) + fmaxf(hd.y + hs1.y + et1.y, 0.f)
               + fmaxf(hd.y + hs2.y + et2.y, 0.f) + fmaxf(hd.y + hs3.y + et3.y, 0.f);
        acc.z += fmaxf(hd.z + hs0.z + et0.z, 0.f) + fmaxf(hd.z + hs1.z + et1.z, 0.f)
               + fmaxf(hd.z + hs2.z + et2.z, 0.f) + fmaxf(hd.z + hs3.z + et3.z, 0.f);
        acc.w += fmaxf(hd.w + hs0.w + et0.w, 0.f) + fmaxf(hd.w + hs1.w + et1.w, 0.f)
               + fmaxf(hd.w + hs2.w + et2.w, 0.f) + fmaxf(hd.w + hs3.w + et3.w, 0.f);
    }
    for (; e < e1; ++e) {
        int s0 = src_s[e], l0 = lab_s[e];
        float4 hs0 = *(const float4*)&HH[(size_t)s0 * 512 + 256 + c4];
        float4 et0 = *(const float4*)&etp[l0 * 256 + c4];
        acc.x += fmaxf(hd.x + hs0.x + et0.x, 0.f);
        acc.y += fmaxf(hd.y + hs0.y + et0.y, 0.f);
        acc.z += fmaxf(hd.z + hs0.z + et0.z, 0.f);
        acc.w += fmaxf(hd.w + hs0.w + et0.w, 0.f);
    }
    float sv[4] = {acc.x, acc.y, acc.z, acc.w};
    f16x4 ph, pl;
#pragma unroll
    for (int j = 0; j < 4; j++) {
        float s = sv[j] * SCL;
        _Float16 h = (_Float16)s;
        ph[j] = h;
        pl[j] = (_Float16)(s - (float)h);
    }
    *(f16x4*)&Phi[(size_t)i * 256 + c4] = ph;
    *(f16x4*)&Plo[(size_t)i * 256 + c4] = pl;
}

// ---------------- readout ----------------
__global__ void readout_scatter(const _Float16* __restrict__ hhi, const _Float16* __restrict__ hlo,
                                const int* __restrict__ vg, const int* __restrict__ vs,
                                float* __restrict__ sums, int* __restrict__ cnt) {
    int m = blockIdx.x * 2 + (threadIdx.x >> 7);
    int c = threadIdx.x & 127;
    if (m >= N_MENTIONS) return;
    int node = vg[m];
    int v = vs[m];
    size_t idx = (size_t)node * DMODEL + c;
    float x = ((float)hhi[idx] + (float)hlo[idx]) * SCLI;
    atomicAdd(&sums[(size_t)v * DMODEL + c], x);
    if (c == 0) atomicAdd(&cnt[v], 1);
}

__global__ void divide_kernel(float* __restrict__ sums, const int* __restrict__ cnt) {
    int v = blockIdx.x;
    int c = threadIdx.x;  // 128
    float d = (float)max(cnt[v], 1);
    sums[(size_t)v * DMODEL + c] /= d;
}

// ---------------- launcher ----------------
extern "C" void kernel_launch(void* const* d_in, const int* in_sizes, int n_in,
                              void* d_out, int out_size, void* d_ws, size_t ws_size,
                              hipStream_t stream) {
    const float* node_labels = (const float*)d_in[0];
    const int*   edges       = (const int*)d_in[1];
    const int*   edge_labels = (const int*)d_in[2];
    const int*   var_gather  = (const int*)d_in[3];
    const int*   var_scatter = (const int*)d_in[4];
    const float* enc_W0 = (const float*)d_in[7];
    const float* enc_b0 = (const float*)d_in[8];
    const float* enc_W1 = (const float*)d_in[9];
    const float* enc_b1 = (const float*)d_in[10];
    const float* edge_emb = (const float*)d_in[11];
    const float* mlp_W1 = (const float*)d_in[12];
    const float* mlp_b1 = (const float*)d_in[13];
    const float* mlp_W2 = (const float*)d_in[14];
    const float* mlp_b2 = (const float*)d_in[15];
    const float* dec_W0 = (const float*)d_in[16];
    const float* dec_b0 = (const float*)d_in[17];
    const float* dec_Wl = (const float*)d_in[18];
    const float* dec_bl = (const float*)d_in[19];
    float* out = (float*)d_out;

    char* ws = (char*)d_ws;
    size_t off = 0;
    auto alloc = [&](size_t bytes) -> void* {
        void* p = ws + off;
        off += (bytes + 255) & ~(size_t)255;
        return p;
    };
    float*    HH    = (float*)alloc((size_t)N_NODES * 512 * 4);       // 102.4 MB
    _Float16* hhi   = (_Float16*)alloc((size_t)N_NODES * DMODEL * 2);
    _Float16* hlo   = (_Float16*)alloc((size_t)N_NODES * DMODEL * 2);
    _Float16* Phi   = (_Float16*)alloc((size_t)N_NODES * 256 * 2);
    _Float16* Plo   = (_Float16*)alloc((size_t)N_NODES * 256 * 2);
    float* etp_all = (float*)alloc((size_t)N_LAYERS * N_ETYPES * 256 * 4);
    int* deg    = (int*)alloc((size_t)N_NODES * 4);
    int* offs   = (int*)alloc((size_t)(N_NODES + 1) * 4);
    int* cursor = (int*)alloc((size_t)N_NODES * 4);
    int* bsum   = (int*)alloc(64 * 4);
    int* src_s  = (int*)alloc((size_t)N_EDGES * 4);
    int* lab_s  = (int*)alloc((size_t)N_EDGES * 4);
    _Float16* W1t_h = (_Float16*)alloc((size_t)N_LAYERS * 512 * 128 * 2);
    _Float16* W1t_l = (_Float16*)alloc((size_t)N_LAYERS * 512 * 128 * 2);
    _Float16* W2t_h = (_Float16*)alloc((size_t)N_LAYERS * 128 * 256 * 2);
    _Float16* W2t_l = (_Float16*)alloc((size_t)N_LAYERS * 128 * 256 * 2);
    _Float16* e0h = (_Float16*)alloc(128 * 64 * 2);
    _Float16* e0l = (_Float16*)alloc(128 * 64 * 2);
    _Float16* e1h = (_Float16*)alloc(128 * 128 * 2);
    _Float16* e1l = (_Float16*)alloc(128 * 128 * 2);
    _Float16* d0h = (_Float16*)alloc(128 * 128 * 2);
    _Float16* d0l = (_Float16*)alloc(128 * 128 * 2);
    _Float16* dlh = (_Float16*)alloc(128 * 128 * 2);
    _Float16* dll = (_Float16*)alloc(128 * 128 * 2);
    _Float16* hench = (_Float16*)alloc((size_t)N_NODES * DMODEL * 2);
    _Float16* hencl = (_Float16*)alloc((size_t)N_NODES * DMODEL * 2);
    float* vsum = (float*)alloc((size_t)N_VARS * DMODEL * 4);
    int*   vcnt = (int*)alloc((size_t)N_VARS * 4);
    _Float16* dtmph = (_Float16*)alloc((size_t)N_VARS * DMODEL * 2);
    _Float16* dtmpl = (_Float16*)alloc((size_t)N_VARS * DMODEL * 2);

    const int* e_src = edges;
    const int* e_dst = edges + N_EDGES;

    hipMemsetAsync(deg, 0, (size_t)N_NODES * 4, stream);
    hipMemsetAsync(vsum, 0, (size_t)N_VARS * DMODEL * 4, stream);
    hipMemsetAsync(vcnt, 0, (size_t)N_VARS * 4, stream);

    // CSR build (hierarchical scan)
    count_deg<<<(N_EDGES + 255) / 256, 256, 0, stream>>>(e_dst, deg);
    scan_local<<<SCAN_NB, SCAN_B, 0, stream>>>(deg, offs, bsum, N_NODES);
    scan_block<<<1, 64, 0, stream>>>(bsum, SCAN_NB);
    scan_final<<<SCAN_NB, SCAN_B, 0, stream>>>(offs, bsum, cursor, N_NODES, N_EDGES);
    place_edges<<<(N_EDGES + 255) / 256, 256, 0, stream>>>(e_src, e_dst, edge_labels, cursor,
                                                           src_s, lab_s);

    // weight prep
    dim3 pb(16, 16);
    wprep<<<dim3(32, 8, N_LAYERS), pb, 0, stream>>>(mlp_W1, W1t_h, W1t_l, 128, 512, 512,
                                                    (long)384 * 256, (long)512 * 128, 1);
    wprep<<<dim3(8, 16, N_LAYERS), pb, 0, stream>>>(mlp_W2, W2t_h, W2t_l, 256, 128, 128,
                                                    (long)256 * 128, (long)128 * 256, 0);
    wprep<<<dim3(8, 4, 1), pb, 0, stream>>>(enc_W0, e0h, e0l, 64, 128, 128, 0, 0, 0);
    wprep<<<dim3(8, 8, 1), pb, 0, stream>>>(enc_W1, e1h, e1l, 128, 128, 128, 0, 0, 0);
    wprep<<<dim3(8, 8, 1), pb, 0, stream>>>(dec_W0, d0h, d0l, 128, 128, 128, 0, 0, 0);
    wprep<<<dim3(8, 8, 1), pb, 0, stream>>>(dec_Wl, dlh, dll, 128, 100, 128, 0, 0, 0);

    // all-layer etype projections, one dispatch
    etype_proj_all<<<dim3(N_ETYPES, N_LAYERS), 256, 0, stream>>>(edge_emb, mlp_W1, mlp_b1, etp_all);

    dim3 blk(256);
    const int MT_N = (N_NODES + 63) / 64;    // 782
    const int MT_V = (N_VARS + 63) / 64;     // 313

    // encoder
    gemm3h<EPI_BIAS_RELU, 0, 1><<<dim3(2, MT_N), blk, 0, stream>>>(
        node_labels, nullptr, nullptr, e0h, e0l, enc_b0, nullptr,
        nullptr, hench, hencl, N_NODES, 128, 64, 128);
    gemm3h<EPI_BIAS, 1, 1><<<dim3(2, MT_N), blk, 0, stream>>>(
        nullptr, hench, hencl, e1h, e1l, enc_b1, nullptr,
        nullptr, hhi, hlo, N_NODES, 128, 128, 128);

    // layer 0 W1 (standalone, from encoder h)
    gemm3h<EPI_NONE, 1, 0><<<dim3(8, MT_N), blk, 0, stream>>>(
        nullptr, hhi, hlo, W1t_h, W1t_l,
        nullptr, nullptr, HH, nullptr, nullptr, N_NODES, 512, 128, 512);

    // message-passing layers: edge_agg(l) then fused W2(l)+W1(l+1); last layer W2 standalone
    for (int l = 0; l < N_LAYERS; ++l) {
        edge_agg<<<(N_NODES + 3) / 4, blk, 0, stream>>>(
            HH, etp_all + (size_t)l * N_ETYPES * 256, offs, src_s, lab_s, Phi, Plo);
        if (l < N_LAYERS - 1) {
            w2w1<<<MT_N, blk, 0, stream>>>(
                Phi, Plo, W2t_h + (size_t)l * 128 * 256, W2t_l + (size_t)l * 128 * 256,
                mlp_b2 + (size_t)l * DMODEL, deg,
                W1t_h + (size_t)(l + 1) * 512 * 128, W1t_l + (size_t)(l + 1) * 512 * 128, HH);
        } else {
            gemm3h<EPI_DEG_GELU, 1, 1><<<dim3(2, MT_N), blk, 0, stream>>>(
                nullptr, Phi, Plo, W2t_h + (size_t)l * 128 * 256, W2t_l + (size_t)l * 128 * 256,
                mlp_b2 + (size_t)l * DMODEL, deg, nullptr, hhi, hlo, N_NODES, 128, 256, 128);
        }
    }

    // readout: scatter-mean into variables
    readout_scatter<<<(N_MENTIONS + 1) / 2, 256, 0, stream>>>(hhi, hlo, var_gather, var_scatter,
                                                              vsum, vcnt);
    divide_kernel<<<N_VARS, DMODEL, 0, stream>>>(vsum, vcnt);

    // decoder
    gemm3h<EPI_BIAS_RELU, 0, 1><<<dim3(2, MT_V), blk, 0, stream>>>(
        vsum, nullptr, nullptr, d0h, d0l, dec_b0, nullptr,
        nullptr, dtmph, dtmpl, N_VARS, 128, 128, 128);
    gemm3h<EPI_BIAS, 1, 0><<<dim3(2, MT_V), blk, 0, stream>>>(
        nullptr, dtmph, dtmpl, dlh, dll, dec_bl, nullptr,
        out, nullptr, nullptr, N_VARS, OUT_DIM, 128, OUT_DIM);
}

// Round 11
// 1712.317 us; speedup vs baseline: 1.4671x; 1.4671x over previous
//
#include <hip/hip_runtime.h>
#include <math.h>

#define N_NODES 50000
#define N_EDGES 600000
#define IN_DIM 64
#define DMODEL 128
#define N_LAYERS 8
#define N_ETYPES 44
#define N_MENTIONS 100000
#define N_VARS 20000
#define OUT_DIM 100

#define EPI_BIAS 0
#define EPI_BIAS_RELU 1
#define EPI_DEG_GELU 2
#define EPI_NONE 3

#define SCL  6.103515625e-05f   /* 2^-14: pre-scale into f16 range (|h| can reach ~1e7) */
#define SCLI 16384.0f

typedef _Float16 f16x8 __attribute__((ext_vector_type(8)));
typedef _Float16 f16x4 __attribute__((ext_vector_type(4)));
typedef float f32x4 __attribute__((ext_vector_type(4)));

__device__ __forceinline__ float gelu_exact(float x) {
    return 0.5f * x * (1.0f + erff(x * 0.70710678118654752f));
}

// ---------------- weight prep: transpose [K,N]->[Npad,K] and split fp32 -> f16 hi+lo ----------
__global__ void wprep(const float* __restrict__ src, _Float16* __restrict__ dhi,
                      _Float16* __restrict__ dlo, int K, int Nsrc, int Npad,
                      long srcLS, long dstLS, int cat) {
    __shared__ float sh[16][17];
    int z = blockIdx.z;
    src += (size_t)z * srcLS;
    dhi += (size_t)z * dstLS;
    dlo += (size_t)z * dstLS;
    int n0 = blockIdx.x * 16, k0 = blockIdx.y * 16;
    int tx = threadIdx.x, ty = threadIdx.y;
    int nr = n0 + tx, kr = k0 + ty;
    float v;
    if (cat) {
        int half = nr >> 8;
        int nc = nr & 255;
        v = src[(size_t)(kr + half * 128) * 256 + nc];
    } else {
        v = (nr < Nsrc) ? src[(size_t)kr * Nsrc + nr] : 0.f;
    }
    sh[ty][tx] = v;
    __syncthreads();
    float x = sh[tx][ty];
    int n = n0 + ty, k = k0 + tx;
    _Float16 hi = (_Float16)x;
    float lo = x - (float)hi;
    dhi[(size_t)n * K + k] = hi;
    dlo[(size_t)n * K + k] = (_Float16)lo;
}

// ---------------- 3xF16 MFMA GEMM, 64x64 tile (encoder/decoder) ----------------
template<int EPI, int ASPLIT, int OSPLIT>
__global__ __launch_bounds__(256) void gemm3h(
        const float* __restrict__ A, const _Float16* __restrict__ Ahi,
        const _Float16* __restrict__ Alo,
        const _Float16* __restrict__ Bh, const _Float16* __restrict__ Bl,
        const float* __restrict__ bias, const int* __restrict__ deg,
        float* __restrict__ C, _Float16* __restrict__ Chi, _Float16* __restrict__ Clo,
        int M, int N, int K, int ldC) {
    __shared__ _Float16 Ah[64 * 56], Al[64 * 56], Bsh[64 * 56], Bsl[64 * 56];
    int t = threadIdx.x;
    int m0 = blockIdx.y * 64, n0 = blockIdx.x * 64;
    int ar = t >> 2, ac = (t & 3) * 8;
    int btt = t & 127, br = btt >> 1, bc = (btt & 1) * 16;
    const _Float16* Bsrc = (t < 128) ? Bh : Bl;
    _Float16* Bdst = (t < 128) ? Bsh : Bsl;
    int lane = t & 63, wid = t >> 6;
    int wm = (wid >> 1) * 32, wn = (wid & 1) * 32;
    int quad = lane >> 4, l15 = lane & 15;
    f32x4 acc[2][2] = {};
    bool arow_ok = (m0 + ar) < M;
    const float* Aptr = ASPLIT ? nullptr : (A + (size_t)(m0 + ar) * K + ac);
    const _Float16* Ahp = ASPLIT ? (Ahi + (size_t)(m0 + ar) * K + ac) : nullptr;
    const _Float16* Alp = ASPLIT ? (Alo + (size_t)(m0 + ar) * K + ac) : nullptr;
    const _Float16* Bptr = Bsrc + (size_t)(n0 + br) * K + bc;

    for (int k0 = 0; k0 < K; k0 += 32) {
        f16x8 hv = {}, lv = {};
        if (ASPLIT) {
            if (arow_ok) {
                hv = *(const f16x8*)(Ahp + k0);
                lv = *(const f16x8*)(Alp + k0);
            }
        } else {
            float4 v0 = {0, 0, 0, 0}, v1 = {0, 0, 0, 0};
            if (arow_ok) {
                v0 = *(const float4*)(Aptr + k0);
                v1 = *(const float4*)(Aptr + k0 + 4);
            }
            float xs[8] = {v0.x, v0.y, v0.z, v0.w, v1.x, v1.y, v1.z, v1.w};
#pragma unroll
            for (int j = 0; j < 8; j++) {
                float s = xs[j] * SCL;
                _Float16 h = (_Float16)s;
                hv[j] = h;
                lv[j] = (_Float16)(s - (float)h);
            }
        }
        *(f16x8*)&Ah[ar * 56 + ac] = hv;
        *(f16x8*)&Al[ar * 56 + ac] = lv;
        f16x8 b0 = *(const f16x8*)(Bptr + k0);
        f16x8 b1v = *(const f16x8*)(Bptr + k0 + 8);
        *(f16x8*)&Bdst[br * 56 + bc] = b0;
        *(f16x8*)&Bdst[br * 56 + bc + 8] = b1v;
        __syncthreads();

        f16x8 afh[2], afl[2], bfh[2], bfl[2];
#pragma unroll
        for (int i = 0; i < 2; i++) {
            int am = (wm + i * 16 + l15) * 56 + quad * 8;
            afh[i] = *(const f16x8*)&Ah[am];
            afl[i] = *(const f16x8*)&Al[am];
            int bn = (wn + i * 16 + l15) * 56 + quad * 8;
            bfh[i] = *(const f16x8*)&Bsh[bn];
            bfl[i] = *(const f16x8*)&Bsl[bn];
        }
#pragma unroll
        for (int i = 0; i < 2; i++)
#pragma unroll
            for (int j = 0; j < 2; j++) {
                acc[i][j] = __builtin_amdgcn_mfma_f32_16x16x32_f16(afh[i], bfh[j], acc[i][j], 0, 0, 0);
                acc[i][j] = __builtin_amdgcn_mfma_f32_16x16x32_f16(afh[i], bfl[j], acc[i][j], 0, 0, 0);
                acc[i][j] = __builtin_amdgcn_mfma_f32_16x16x32_f16(afl[i], bfh[j], acc[i][j], 0, 0, 0);
            }
        __syncthreads();
    }

#pragma unroll
    for (int i = 0; i < 2; i++) {
        int rowb = m0 + wm + i * 16 + quad * 4;
#pragma unroll
        for (int j = 0; j < 2; j++) {
            int col = n0 + wn + j * 16 + l15;
            if (col >= N) continue;
#pragma unroll
            for (int r = 0; r < 4; r++) {
                int row = rowb + r;
                if (row >= M) continue;
                float v = acc[i][j][r] * SCLI;
                if (EPI == EPI_BIAS) { v += bias[col]; }
                else if (EPI == EPI_BIAS_RELU) { v += bias[col]; v = fmaxf(v, 0.f); }
                else if (EPI == EPI_DEG_GELU) { v += (float)deg[row] * bias[col]; v = gelu_exact(v); }
                size_t idx = (size_t)row * ldC + col;
                if (OSPLIT) {
                    float s = v * SCL;
                    _Float16 h = (_Float16)s;
                    Chi[idx] = h;
                    Clo[idx] = (_Float16)(s - (float)h);
                } else {
                    C[idx] = v;
                }
            }
        }
    }
}

// ---------------- 3xF16 MFMA GEMM v2: 64x128 block tile, 32x64 wave tiles ----------------
// Per-wave k-chunk: 12 ds_read_b128 (~144cyc) vs 24 MFMA (~115cyc) — better LDS:MFMA balance
// than the 64x64 kernel (96 vs 58). A pre-split hi/lo only. Same accumulation order -> bit-exact.
template<int EPI, int OSPLIT>
__global__ __launch_bounds__(256) void gemm3h_v2(
        const _Float16* __restrict__ Ahi, const _Float16* __restrict__ Alo,
        const _Float16* __restrict__ Bh, const _Float16* __restrict__ Bl,
        const float* __restrict__ bias, const int* __restrict__ deg,
        float* __restrict__ C, _Float16* __restrict__ Chi, _Float16* __restrict__ Clo,
        int M, int N, int K, int ldC) {
    __shared__ _Float16 Ah[64 * 56], Al[64 * 56], Bsh[128 * 56], Bsl[128 * 56];
    int t = threadIdx.x;
    int m0 = blockIdx.y * 64, n0 = blockIdx.x * 128;
    int lane = t & 63, wid = t >> 6;
    int wm = (wid >> 1) * 32, wn = (wid & 1) * 64;
    int quad = lane >> 4, l15 = lane & 15;
    f32x4 acc[2][4] = {};

    for (int k0 = 0; k0 < K; k0 += 32) {
        // stage 1536 16B units: it0=A-hi, it1=A-lo, it2/3=B-hi, it4/5=B-lo
#pragma unroll
        for (int it = 0; it < 6; it++) {
            int u = it * 256 + t;
            int seg = u & 3;
            f16x8 d = {};
            if (it < 2) {
                int row = (u >> 2) & 63;
                int g = m0 + row;
                const _Float16* src = (it == 0) ? Ahi : Alo;
                if (g < M) d = *(const f16x8*)(src + (size_t)g * K + k0 + seg * 8);
                _Float16* dst = (it == 0) ? Ah : Al;
                *(f16x8*)&dst[row * 56 + seg * 8] = d;
            } else {
                int v = u - 512;
                int row = (v >> 2) & 127;
                const _Float16* src = (v < 512) ? Bh : Bl;
                d = *(const f16x8*)(src + (size_t)(n0 + row) * K + k0 + seg * 8);
                _Float16* dst = (v < 512) ? Bsh : Bsl;
                *(f16x8*)&dst[row * 56 + seg * 8] = d;
            }
        }
        __syncthreads();

        f16x8 afh[2], afl[2], bfh[4], bfl[4];
#pragma unroll
        for (int i = 0; i < 2; i++) {
            int am = (wm + i * 16 + l15) * 56 + quad * 8;
            afh[i] = *(const f16x8*)&Ah[am];
            afl[i] = *(const f16x8*)&Al[am];
        }
#pragma unroll
        for (int j = 0; j < 4; j++) {
            int bn = (wn + j * 16 + l15) * 56 + quad * 8;
            bfh[j] = *(const f16x8*)&Bsh[bn];
            bfl[j] = *(const f16x8*)&Bsl[bn];
        }
#pragma unroll
        for (int i = 0; i < 2; i++)
#pragma unroll
            for (int j = 0; j < 4; j++) {
                acc[i][j] = __builtin_amdgcn_mfma_f32_16x16x32_f16(afh[i], bfh[j], acc[i][j], 0, 0, 0);
                acc[i][j] = __builtin_amdgcn_mfma_f32_16x16x32_f16(afh[i], bfl[j], acc[i][j], 0, 0, 0);
                acc[i][j] = __builtin_amdgcn_mfma_f32_16x16x32_f16(afl[i], bfh[j], acc[i][j], 0, 0, 0);
            }
        __syncthreads();
    }

#pragma unroll
    for (int i = 0; i < 2; i++) {
        int rowb = m0 + wm + i * 16 + quad * 4;
#pragma unroll
        for (int j = 0; j < 4; j++) {
            int col = n0 + wn + j * 16 + l15;
            if (col >= N) continue;
#pragma unroll
            for (int r = 0; r < 4; r++) {
                int row = rowb + r;
                if (row >= M) continue;
                float v = acc[i][j][r] * SCLI;
                if (EPI == EPI_BIAS) { v += bias[col]; }
                else if (EPI == EPI_BIAS_RELU) { v += bias[col]; v = fmaxf(v, 0.f); }
                else if (EPI == EPI_DEG_GELU) { v += (float)deg[row] * bias[col]; v = gelu_exact(v); }
                size_t idx = (size_t)row * ldC + col;
                if (OSPLIT) {
                    float s = v * SCL;
                    _Float16 h = (_Float16)s;
                    Chi[idx] = h;
                    Clo[idx] = (_Float16)(s - (float)h);
                } else {
                    C[idx] = v;
                }
            }
        }
    }
}

// ---------------- CSR build ----------------
__global__ void count_deg(const int* __restrict__ dst, int* __restrict__ deg) {
    int e = blockIdx.x * blockDim.x + threadIdx.x;
    if (e < N_EDGES) atomicAdd(&deg[dst[e]], 1);
}

#define SCAN_B 1024
#define SCAN_NB ((N_NODES + SCAN_B - 1) / SCAN_B)

__global__ void scan_local(const int* __restrict__ deg, int* __restrict__ offs,
                           int* __restrict__ bsum, int n) {
    __shared__ int sh[SCAN_B];
    int t = threadIdx.x;
    int i = blockIdx.x * SCAN_B + t;
    int v = (i < n) ? deg[i] : 0;
    sh[t] = v;
    __syncthreads();
    for (int o = 1; o < SCAN_B; o <<= 1) {
        int u = (t >= o) ? sh[t - o] : 0;
        __syncthreads();
        sh[t] += u;
        __syncthreads();
    }
    if (i < n) offs[i] = sh[t] - v;
    if (t == SCAN_B - 1) bsum[blockIdx.x] = sh[t];
}

__global__ void scan_block(int* __restrict__ bsum, int nb) {
    __shared__ int sh[64];
    int t = threadIdx.x;
    int v = (t < nb) ? bsum[t] : 0;
    sh[t] = v;
    __syncthreads();
    for (int o = 1; o < 64; o <<= 1) {
        int u = (t >= o) ? sh[t - o] : 0;
        __syncthreads();
        sh[t] += u;
        __syncthreads();
    }
    if (t < nb) bsum[t] = sh[t] - v;
}

__global__ void scan_final(int* __restrict__ offs, const int* __restrict__ bsum,
                           int* __restrict__ cursor, int n, int total) {
    int i = blockIdx.x * SCAN_B + threadIdx.x;
    if (i < n) {
        int o = offs[i] + bsum[blockIdx.x];
        offs[i] = o;
        cursor[i] = o;
    }
    if (i == n) offs[n] = total;
}

__global__ void place_edges(const int* __restrict__ src, const int* __restrict__ dst,
                            const int* __restrict__ lab, int* __restrict__ cursor,
                            int* __restrict__ src_s, int* __restrict__ lab_s) {
    int e = blockIdx.x * blockDim.x + threadIdx.x;
    if (e < N_EDGES) {
        int pos = atomicAdd(&cursor[dst[e]], 1);
        src_s[pos] = src[e];
        lab_s[pos] = lab[e];
    }
}

// ---------------- per-etype projection, all layers in one dispatch ----------------
__global__ void etype_proj_all(const float* __restrict__ edge_emb, const float* __restrict__ mlp_W1,
                               const float* __restrict__ mlp_b1, float* __restrict__ etp_all) {
    int et = blockIdx.x;
    int l  = blockIdx.y;
    int c = threadIdx.x;  // 256
    const float* ee = edge_emb + (size_t)l * N_ETYPES * DMODEL + (size_t)et * DMODEL;
    const float* W  = mlp_W1 + (size_t)l * 384 * 256 + (size_t)256 * 256;
    float s = mlp_b1[(size_t)l * 256 + c];
    for (int k = 0; k < DMODEL; k++)
        s += ee[k] * W[(size_t)k * 256 + c];
    etp_all[((size_t)l * N_ETYPES + et) * 256 + c] = s;
}

// ---------------- edge aggregation: wave-per-node, unroll x4 (round-6 proven form) ----------------
__global__ __launch_bounds__(256) void edge_agg(
        const float* __restrict__ HH, const float* __restrict__ etp,
        const int* __restrict__ offsets, const int* __restrict__ src_s,
        const int* __restrict__ lab_s, _Float16* __restrict__ Phi,
        _Float16* __restrict__ Plo) {
    int wid = threadIdx.x >> 6, tl = threadIdx.x & 63;
    int i = blockIdx.x * 4 + wid;
    if (i >= N_NODES) return;
    int c4 = tl * 4;
    float4 hd = *(const float4*)&HH[(size_t)i * 512 + c4];
    float4 acc = {0.f, 0.f, 0.f, 0.f};
    int e0 = offsets[i], e1 = offsets[i + 1];
    int e = e0;
    for (; e + 3 < e1; e += 4) {
        int s0 = src_s[e],     l0 = lab_s[e];
        int s1 = src_s[e + 1], l1 = lab_s[e + 1];
        int s2 = src_s[e + 2], l2 = lab_s[e + 2];
        int s3 = src_s[e + 3], l3 = lab_s[e + 3];
        float4 hs0 = *(const float4*)&HH[(size_t)s0 * 512 + 256 + c4];
        float4 hs1 = *(const float4*)&HH[(size_t)s1 * 512 + 256 + c4];
        float4 hs2 = *(const float4*)&HH[(size_t)s2 * 512 + 256 + c4];
        float4 hs3 = *(const float4*)&HH[(size_t)s3 * 512 + 256 + c4];
        float4 et0 = *(const float4*)&etp[l0 * 256 + c4];
        float4 et1 = *(const float4*)&etp[l1 * 256 + c4];
        float4 et2 = *(const float4*)&etp[l2 * 256 + c4];
        float4 et3 = *(const float4*)&etp[l3 * 256 + c4];
        acc.x += fmaxf(hd.x + hs0.x + et0.x, 0.f) + fmaxf(hd.x + hs1.x + et1.x, 0.f)
               + fmaxf(hd.x + hs2.x + et2.x, 0.f) + fmaxf(hd.x + hs3.x + et3.x, 0.f);
        acc.y += fmaxf(hd.y + hs0.y + et0.y, 0.f) + fmaxf(hd.y + hs1.y + et1.y, 0.f)
               + fmaxf(hd.y + hs2.y + et2.y, 0.f) + fmaxf(hd.y + hs3.y + et3.y, 0.f);
        acc.z += fmaxf(hd.z + hs0.z + et0.z, 0.f) + fmaxf(hd.z + hs1.z + et1.z, 0.f)
               + fmaxf(hd.z + hs2.z + et2.z, 0.f) + fmaxf(hd.z + hs3.z + et3.z, 0.f);
        acc.w += fmaxf(hd.w + hs0.w + et0.w, 0.f) + fmaxf(hd.w + hs1.w + et1.w, 0.f)
               + fmaxf(hd.w + hs2.w + et2.w, 0.f) + fmaxf(hd.w + hs3.w + et3.w, 0.f);
    }
    for (; e < e1; ++e) {
        int s0 = src_s[e], l0 = lab_s[e];
        float4 hs0 = *(const float4*)&HH[(size_t)s0 * 512 + 256 + c4];
        float4 et0 = *(const float4*)&etp[l0 * 256 + c4];
        acc.x += fmaxf(hd.x + hs0.x + et0.x, 0.f);
        acc.y += fmaxf(hd.y + hs0.y + et0.y, 0.f);
        acc.z += fmaxf(hd.z + hs0.z + et0.z, 0.f);
        acc.w += fmaxf(hd.w + hs0.w + et0.w, 0.f);
    }
    float sv[4] = {acc.x, acc.y, acc.z, acc.w};
    f16x4 ph, pl;
#pragma unroll
    for (int j = 0; j < 4; j++) {
        float s = sv[j] * SCL;
        _Float16 h = (_Float16)s;
        ph[j] = h;
        pl[j] = (_Float16)(s - (float)h);
    }
    *(f16x4*)&Phi[(size_t)i * 256 + c4] = ph;
    *(f16x4*)&Plo[(size_t)i * 256 + c4] = pl;
}

// ---------------- readout ----------------
__global__ void readout_scatter(const _Float16* __restrict__ hhi, const _Float16* __restrict__ hlo,
                                const int* __restrict__ vg, const int* __restrict__ vs,
                                float* __restrict__ sums, int* __restrict__ cnt) {
    int m = blockIdx.x * 2 + (threadIdx.x >> 7);
    int c = threadIdx.x & 127;
    if (m >= N_MENTIONS) return;
    int node = vg[m];
    int v = vs[m];
    size_t idx = (size_t)node * DMODEL + c;
    float x = ((float)hhi[idx] + (float)hlo[idx]) * SCLI;
    atomicAdd(&sums[(size_t)v * DMODEL + c], x);
    if (c == 0) atomicAdd(&cnt[v], 1);
}

__global__ void divide_kernel(float* __restrict__ sums, const int* __restrict__ cnt) {
    int v = blockIdx.x;
    int c = threadIdx.x;  // 128
    float d = (float)max(cnt[v], 1);
    sums[(size_t)v * DMODEL + c] /= d;
}

// ---------------- launcher ----------------
extern "C" void kernel_launch(void* const* d_in, const int* in_sizes, int n_in,
                              void* d_out, int out_size, void* d_ws, size_t ws_size,
                              hipStream_t stream) {
    const float* node_labels = (const float*)d_in[0];
    const int*   edges       = (const int*)d_in[1];
    const int*   edge_labels = (const int*)d_in[2];
    const int*   var_gather  = (const int*)d_in[3];
    const int*   var_scatter = (const int*)d_in[4];
    const float* enc_W0 = (const float*)d_in[7];
    const float* enc_b0 = (const float*)d_in[8];
    const float* enc_W1 = (const float*)d_in[9];
    const float* enc_b1 = (const float*)d_in[10];
    const float* edge_emb = (const float*)d_in[11];
    const float* mlp_W1 = (const float*)d_in[12];
    const float* mlp_b1 = (const float*)d_in[13];
    const float* mlp_W2 = (const float*)d_in[14];
    const float* mlp_b2 = (const float*)d_in[15];
    const float* dec_W0 = (const float*)d_in[16];
    const float* dec_b0 = (const float*)d_in[17];
    const float* dec_Wl = (const float*)d_in[18];
    const float* dec_bl = (const float*)d_in[19];
    float* out = (float*)d_out;

    char* ws = (char*)d_ws;
    size_t off = 0;
    auto alloc = [&](size_t bytes) -> void* {
        void* p = ws + off;
        off += (bytes + 255) & ~(size_t)255;
        return p;
    };
    float*    HH    = (float*)alloc((size_t)N_NODES * 512 * 4);       // 102.4 MB
    _Float16* hhi   = (_Float16*)alloc((size_t)N_NODES * DMODEL * 2);
    _Float16* hlo   = (_Float16*)alloc((size_t)N_NODES * DMODEL * 2);
    _Float16* Phi   = (_Float16*)alloc((size_t)N_NODES * 256 * 2);
    _Float16* Plo   = (_Float16*)alloc((size_t)N_NODES * 256 * 2);
    float* etp_all = (float*)alloc((size_t)N_LAYERS * N_ETYPES * 256 * 4);
    int* deg    = (int*)alloc((size_t)N_NODES * 4);
    int* offs   = (int*)alloc((size_t)(N_NODES + 1) * 4);
    int* cursor = (int*)alloc((size_t)N_NODES * 4);
    int* bsum   = (int*)alloc(64 * 4);
    int* src_s  = (int*)alloc((size_t)N_EDGES * 4);
    int* lab_s  = (int*)alloc((size_t)N_EDGES * 4);
    _Float16* W1t_h = (_Float16*)alloc((size_t)N_LAYERS * 512 * 128 * 2);
    _Float16* W1t_l = (_Float16*)alloc((size_t)N_LAYERS * 512 * 128 * 2);
    _Float16* W2t_h = (_Float16*)alloc((size_t)N_LAYERS * 128 * 256 * 2);
    _Float16* W2t_l = (_Float16*)alloc((size_t)N_LAYERS * 128 * 256 * 2);
    _Float16* e0h = (_Float16*)alloc(128 * 64 * 2);
    _Float16* e0l = (_Float16*)alloc(128 * 64 * 2);
    _Float16* e1h = (_Float16*)alloc(128 * 128 * 2);
    _Float16* e1l = (_Float16*)alloc(128 * 128 * 2);
    _Float16* d0h = (_Float16*)alloc(128 * 128 * 2);
    _Float16* d0l = (_Float16*)alloc(128 * 128 * 2);
    _Float16* dlh = (_Float16*)alloc(128 * 128 * 2);
    _Float16* dll = (_Float16*)alloc(128 * 128 * 2);
    _Float16* hench = (_Float16*)alloc((size_t)N_NODES * DMODEL * 2);
    _Float16* hencl = (_Float16*)alloc((size_t)N_NODES * DMODEL * 2);
    float* vsum = (float*)alloc((size_t)N_VARS * DMODEL * 4);
    int*   vcnt = (int*)alloc((size_t)N_VARS * 4);
    _Float16* dtmph = (_Float16*)alloc((size_t)N_VARS * DMODEL * 2);
    _Float16* dtmpl = (_Float16*)alloc((size_t)N_VARS * DMODEL * 2);

    const int* e_src = edges;
    const int* e_dst = edges + N_EDGES;

    hipMemsetAsync(deg, 0, (size_t)N_NODES * 4, stream);
    hipMemsetAsync(vsum, 0, (size_t)N_VARS * DMODEL * 4, stream);
    hipMemsetAsync(vcnt, 0, (size_t)N_VARS * 4, stream);

    // CSR build (hierarchical scan)
    count_deg<<<(N_EDGES + 255) / 256, 256, 0, stream>>>(e_dst, deg);
    scan_local<<<SCAN_NB, SCAN_B, 0, stream>>>(deg, offs, bsum, N_NODES);
    scan_block<<<1, 64, 0, stream>>>(bsum, SCAN_NB);
    scan_final<<<SCAN_NB, SCAN_B, 0, stream>>>(offs, bsum, cursor, N_NODES, N_EDGES);
    place_edges<<<(N_EDGES + 255) / 256, 256, 0, stream>>>(e_src, e_dst, edge_labels, cursor,
                                                           src_s, lab_s);

    // weight prep
    dim3 pb(16, 16);
    wprep<<<dim3(32, 8, N_LAYERS), pb, 0, stream>>>(mlp_W1, W1t_h, W1t_l, 128, 512, 512,
                                                    (long)384 * 256, (long)512 * 128, 1);
    wprep<<<dim3(8, 16, N_LAYERS), pb, 0, stream>>>(mlp_W2, W2t_h, W2t_l, 256, 128, 128,
                                                    (long)256 * 128, (long)128 * 256, 0);
    wprep<<<dim3(8, 4, 1), pb, 0, stream>>>(enc_W0, e0h, e0l, 64, 128, 128, 0, 0, 0);
    wprep<<<dim3(8, 8, 1), pb, 0, stream>>>(enc_W1, e1h, e1l, 128, 128, 128, 0, 0, 0);
    wprep<<<dim3(8, 8, 1), pb, 0, stream>>>(dec_W0, d0h, d0l, 128, 128, 128, 0, 0, 0);
    wprep<<<dim3(8, 8, 1), pb, 0, stream>>>(dec_Wl, dlh, dll, 128, 100, 128, 0, 0, 0);

    // all-layer etype projections, one dispatch
    etype_proj_all<<<dim3(N_ETYPES, N_LAYERS), 256, 0, stream>>>(edge_emb, mlp_W1, mlp_b1, etp_all);

    dim3 blk(256);
    const int MT_N = (N_NODES + 63) / 64;    // 782
    const int MT_V = (N_VARS + 63) / 64;     // 313

    // encoder
    gemm3h<EPI_BIAS_RELU, 0, 1><<<dim3(2, MT_N), blk, 0, stream>>>(
        node_labels, nullptr, nullptr, e0h, e0l, enc_b0, nullptr,
        nullptr, hench, hencl, N_NODES, 128, 64, 128);
    gemm3h<EPI_BIAS, 1, 1><<<dim3(2, MT_N), blk, 0, stream>>>(
        nullptr, hench, hencl, e1h, e1l, enc_b1, nullptr,
        nullptr, hhi, hlo, N_NODES, 128, 128, 128);

    // message-passing layers
    for (int l = 0; l < N_LAYERS; ++l) {
        gemm3h_v2<EPI_NONE, 0><<<dim3(4, MT_N), blk, 0, stream>>>(
            hhi, hlo, W1t_h + (size_t)l * 512 * 128, W1t_l + (size_t)l * 512 * 128,
            nullptr, nullptr, HH, nullptr, nullptr, N_NODES, 512, 128, 512);
        edge_agg<<<(N_NODES + 3) / 4, blk, 0, stream>>>(
            HH, etp_all + (size_t)l * N_ETYPES * 256, offs, src_s, lab_s, Phi, Plo);
        gemm3h_v2<EPI_DEG_GELU, 1><<<dim3(1, MT_N), blk, 0, stream>>>(
            Phi, Plo, W2t_h + (size_t)l * 128 * 256, W2t_l + (size_t)l * 128 * 256,
            mlp_b2 + (size_t)l * DMODEL, deg, nullptr, hhi, hlo, N_NODES, 128, 256, 128);
    }

    // readout: scatter-mean into variables
    readout_scatter<<<(N_MENTIONS + 1) / 2, 256, 0, stream>>>(hhi, hlo, var_gather, var_scatter,
                                                              vsum, vcnt);
    divide_kernel<<<N_VARS, DMODEL, 0, stream>>>(vsum, vcnt);

    // decoder
    gemm3h<EPI_BIAS_RELU, 0, 1><<<dim3(2, MT_V), blk, 0, stream>>>(
        vsum, nullptr, nullptr, d0h, d0l, dec_b0, nullptr,
        nullptr, dtmph, dtmpl, N_VARS, 128, 128, 128);
    gemm3h<EPI_BIAS, 1, 0><<<dim3(2, MT_V), blk, 0, stream>>>(
        nullptr, dtmph, dtmpl, dlh, dll, dec_bl, nullptr,
        out, nullptr, nullptr, N_VARS, OUT_DIM, 128, OUT_DIM);
}